// Round 8
// baseline (349.026 us; speedup 1.0000x reference)
//
#include <hip/hip_runtime.h>
#include <stdint.h>

#define NB 256
#define NL 128
#define ND1 512
#define ND2 512
#define NE 64

#define BI 128              // i-tile width per block
#define BK 32               // k-tile depth (j-dim)
#define NKT (ND2 / BK)      // 16 k-tiles
#define LDST 40             // LDS row stride (bf16): 80 B rows, 16B-aligned, 20-bank phase/row (2-way on b128 reads = free)
#define BUFSZ ((NL + BI) * LDST)   // one dbuf buffer: sA | sB = 10240 ushorts

typedef float float4_t __attribute__((ext_vector_type(4)));
typedef __bf16 bf16x8_t __attribute__((ext_vector_type(8)));
typedef unsigned short ushort4_t __attribute__((ext_vector_type(4)));
typedef unsigned short ushort8_t __attribute__((ext_vector_type(8)));

// fp32 -> bf16 round-to-nearest-even
__device__ __forceinline__ unsigned short f2bf(float f) {
    unsigned int u = __float_as_uint(f);
    u += 0x7FFFu + ((u >> 16) & 1u);
    return (unsigned short)(u >> 16);
}

__device__ __forceinline__ ushort4_t cvt4(float4_t v) {
    ushort4_t u;
    u.x = f2bf(v.x); u.y = f2bf(v.y); u.z = f2bf(v.z); u.w = f2bf(v.w);
    return u;
}

// Pre-pass: zero output + counting-sort batches by expert id -> perm.
__global__ void pre_kernel(const int* __restrict__ pidx, int* __restrict__ perm,
                           float* __restrict__ out, int zero_n, int do_sort)
{
    const int g = blockIdx.x, t = threadIdx.x;
    const int idx = g * 256 + t;
    if (idx < zero_n) out[idx] = 0.f;
    if (do_sort && g == 0) {
        __shared__ int cnt[NE];
        __shared__ int base[NE];
        if (t < NE) cnt[t] = 0;
        __syncthreads();
        const int e = pidx[t];
        const int r = atomicAdd(&cnt[e], 1);
        __syncthreads();
        if (t == 0) {
            int s = 0;
            for (int i = 0; i < NE; ++i) { base[i] = s; s += cnt[i]; }
        }
        __syncthreads();
        perm[base[e] + r] = t;
    }
}

// Z = T2 (128 x 512) x W^T; out[b,l] = sum_i Z[l,i] * t1[b,l,i]
//
// BI=128, BK=32, 256 threads (4 waves, one per 32 l-rows), grid 1024 =
// EXACTLY 4 blocks/CU x 256 CU, single round, zero tail. LDS dbuf
// 2 x 20 KB = 40960 B/block -> 4 blocks/CU = 160 KiB exactly: 4
// INDEPENDENT barrier groups per CU (vs 2 in the 73 KB version) fill
// each other's barrier/latency stalls. Same proven pipeline: dbuf,
// stage-writes overlap MFMA, loads for kt+2 issue-pinned, ONE
// lgkm+barrier per iteration. acc[2][8] = 64 AGPR; ~64 VGPR -> 4 w/SIMD.
// All s_barriers are in block-uniform control flow (kt guards are
// compile-time after unroll) — no divergent-barrier hang path.
//
// Placement: XCD x = g&7 owns expert-sorted batch slots x*32..x*32+31;
// per-XCD sequence interleaves it=0..3 of each b (weights+t2 L2 reuse).
template <bool USE_PERM>
__global__ __launch_bounds__(256, 4) void pdot_kernel(
    const float* __restrict__ t1, const float* __restrict__ t2,
    const int* __restrict__ pidx, const float* __restrict__ wgt,
    const int* __restrict__ perm, float* __restrict__ out)
{
    __shared__ unsigned short sm[2][BUFSZ];   // [buf][ sA(128 rows) | sB(128 rows) ]

    const int g  = blockIdx.x;
    const int x  = g & 7;                 // XCD
    const int s  = g >> 3;                // per-XCD sequence 0..127
    const int slot = x * 32 + (s >> 2);   // expert-sorted batch slot
    const int b  = USE_PERM ? perm[slot] : slot;
    const int it = s & 3;
    const int i0 = it * BI;

    const int t  = threadIdx.x;
    const int wv = t >> 6;         // wave 0..3 -> l-rows wv*32..wv*32+31
    const int ln = t & 63;
    const int nh = ln & 15;
    const int qd = ln >> 4;

    const int e = pidx[b];
    const float* aPtr = t2  + (size_t)b * (NL * ND2);
    const float* bPtr = wgt + (size_t)e * (ND1 * ND2) + (size_t)i0 * ND2;
    const float* t1p  = t1  + (size_t)b * (NL * ND1) + i0;

    float4_t acc[2][8];
    #pragma unroll
    for (int i = 0; i < 2; ++i)
        #pragma unroll
        for (int j = 0; j < 8; ++j) {
            float4_t z = {0.f, 0.f, 0.f, 0.f};
            acc[i][j] = z;
        }

    // staging map: tile 128 rows x 32 cols fp32 = 8 float4/row; lane (t&7)
    // owns chunk (t&7), row = p*32 + (t>>3), p=0..3. Coalesced 128B/row.
    const int s_row = t >> 3;            // 0..31, +p*32
    const int s_c4  = (t & 7) * 4;       // float (== bf16) col
    const size_t sOff = (size_t)s_row * ND2 + s_c4;
    const int wOffA = s_row * LDST + s_c4;
    const int wOffB = (NL + s_row) * LDST + s_c4;

    float4_t pa[4], pb[4];   // in-flight prefetch (32 VGPRs)

    // ---- prologue: load+stage tile 0 into buf0; issue loads of tile 1 ----
    #pragma unroll
    for (int p = 0; p < 4; ++p) {
        pa[p] = *(const float4_t*)(aPtr + sOff + (size_t)p * (32 * ND2));
        pb[p] = *(const float4_t*)(bPtr + sOff + (size_t)p * (32 * ND2));
    }
    #pragma unroll
    for (int p = 0; p < 4; ++p) {
        *(ushort4_t*)(&sm[0][wOffA + p * (32 * LDST)]) = cvt4(pa[p]);
        *(ushort4_t*)(&sm[0][wOffB + p * (32 * LDST)]) = cvt4(pb[p]);
    }
    #pragma unroll
    for (int p = 0; p < 4; ++p) {
        pa[p] = *(const float4_t*)(aPtr + sOff + BK + (size_t)p * (32 * ND2));
        pb[p] = *(const float4_t*)(bPtr + sOff + BK + (size_t)p * (32 * ND2));
    }
    __builtin_amdgcn_sched_barrier(0);
    asm volatile("s_waitcnt lgkmcnt(0)" ::: "memory");
    __builtin_amdgcn_sched_barrier(0);
    __builtin_amdgcn_s_barrier();
    __builtin_amdgcn_sched_barrier(0);

    #pragma unroll
    for (int kt = 0; kt < NKT; ++kt) {
        const int cur = kt & 1;
        const int nxt = cur ^ 1;
        const unsigned short* cA = &sm[cur][0];
        const unsigned short* cB = &sm[cur][NL * LDST];

        // ---- compute tile kt: one K=32 MFMA step ----
        const int kf = qd * 8;
        const int ra = wv * 32 + nh;
        bf16x8_t af0 = __builtin_bit_cast(bf16x8_t, *(const ushort8_t*)(&cA[(ra     ) * LDST + kf]));
        bf16x8_t af1 = __builtin_bit_cast(bf16x8_t, *(const ushort8_t*)(&cA[(ra + 16) * LDST + kf]));
        bf16x8_t bv[8];
        #pragma unroll
        for (int ns = 0; ns < 8; ++ns)
            bv[ns] = __builtin_bit_cast(bf16x8_t, *(const ushort8_t*)(&cB[(ns * 16 + nh) * LDST + kf]));

        __builtin_amdgcn_s_setprio(1);
        #pragma unroll
        for (int ns = 0; ns < 8; ++ns) {
            acc[0][ns] = __builtin_amdgcn_mfma_f32_16x16x32_bf16(af0, bv[ns], acc[0][ns], 0, 0, 0);
            acc[1][ns] = __builtin_amdgcn_mfma_f32_16x16x32_bf16(af1, bv[ns], acc[1][ns], 0, 0, 0);
        }
        __builtin_amdgcn_s_setprio(0);

        if (kt < NKT - 1) {
            // ---- overlapped stage of tile kt+1 into buf nxt ----
            #pragma unroll
            for (int p = 0; p < 4; ++p) {
                *(ushort4_t*)(&sm[nxt][wOffA + p * (32 * LDST)]) = cvt4(pa[p]);
                *(ushort4_t*)(&sm[nxt][wOffB + p * (32 * LDST)]) = cvt4(pb[p]);
            }
            // ---- issue loads for tile kt+2 (pinned: cannot sink below) ----
            if (kt < NKT - 2) {
                const size_t k0 = (size_t)(kt + 2) * BK;
                #pragma unroll
                for (int p = 0; p < 4; ++p) {
                    pa[p] = *(const float4_t*)(aPtr + sOff + k0 + (size_t)p * (32 * ND2));
                    pb[p] = *(const float4_t*)(bPtr + sOff + k0 + (size_t)p * (32 * ND2));
                }
                __builtin_amdgcn_sched_barrier(0);
            }
            // ---- single barrier per iteration ----
            asm volatile("s_waitcnt lgkmcnt(0)" ::: "memory");
            __builtin_amdgcn_sched_barrier(0);
            __builtin_amdgcn_s_barrier();
            __builtin_amdgcn_sched_barrier(0);
        }
    }

    // epilogue: out[b,l] += sum over this i-tile of Z[l,i]*t1[l,i]
    // C/D: col(n=i) = ns*16+nh, row(m=l) = wv*32 + ms*16 + qd*4 + r
    #pragma unroll
    for (int ms = 0; ms < 2; ++ms) {
        #pragma unroll
        for (int r = 0; r < 4; ++r) {
            const int row = wv * 32 + ms * 16 + qd * 4 + r;
            float ps = 0.f;
            #pragma unroll
            for (int ns = 0; ns < 8; ++ns) {
                const float tv = t1p[(size_t)row * ND1 + ns * 16 + nh];
                ps += acc[ms][ns][r] * tv;
            }
            ps += __shfl_xor(ps, 1);
            ps += __shfl_xor(ps, 2);
            ps += __shfl_xor(ps, 4);
            ps += __shfl_xor(ps, 8);
            if (nh == 0) atomicAdd(&out[b * NL + row], ps);
        }
    }
}

extern "C" void kernel_launch(void* const* d_in, const int* in_sizes, int n_in,
                              void* d_out, int out_size, void* d_ws, size_t ws_size,
                              hipStream_t stream)
{
    const float* t1  = (const float*)d_in[0];
    const float* t2  = (const float*)d_in[1];
    const int* pidx  = (const int*)d_in[2];
    const float* wgt = (const float*)d_in[3];
    float* out = (float*)d_out;

    const int zero_blocks = (out_size + 255) / 256;
    const bool have_ws = ws_size >= NB * sizeof(int);
    int* perm = have_ws ? (int*)d_ws : nullptr;

    pre_kernel<<<dim3(zero_blocks), dim3(256), 0, stream>>>(pidx, perm, out, out_size, have_ws ? 1 : 0);

    if (have_ws)
        pdot_kernel<true><<<dim3(NB * (ND1 / BI)), dim3(256), 0, stream>>>(t1, t2, pidx, wgt, perm, out);
    else
        pdot_kernel<false><<<dim3(NB * (ND1 / BI)), dim3(256), 0, stream>>>(t1, t2, pidx, wgt, nullptr, out);
}

// Round 9
// 207.786 us; speedup vs baseline: 1.6797x; 1.6797x over previous
//
#include <hip/hip_runtime.h>
#include <stdint.h>

#define NB 256
#define NL 128
#define ND1 512
#define ND2 512
#define NE 64

#define BI 128              // i-tile width per block
#define BK 64               // k-tile depth (j-dim)
#define NKT (ND2 / BK)      // 8 k-tiles
#define LDST 72             // LDS row stride (bf16 elems): 144 B rows, 16B-aligned, bank phase +4/row
#define BUFSZ ((NL + BI) * LDST)   // one dbuf buffer: sA then sB

typedef float float4_t __attribute__((ext_vector_type(4)));
typedef __bf16 bf16x8_t __attribute__((ext_vector_type(8)));
typedef unsigned short ushort4_t __attribute__((ext_vector_type(4)));
typedef unsigned short ushort8_t __attribute__((ext_vector_type(8)));

// fp32 -> bf16 round-to-nearest-even
__device__ __forceinline__ unsigned short f2bf(float f) {
    unsigned int u = __float_as_uint(f);
    u += 0x7FFFu + ((u >> 16) & 1u);
    return (unsigned short)(u >> 16);
}

__device__ __forceinline__ ushort4_t cvt4(float4_t v) {
    ushort4_t u;
    u.x = f2bf(v.x); u.y = f2bf(v.y); u.z = f2bf(v.z); u.w = f2bf(v.w);
    return u;
}

// Pre-pass: zero output + counting-sort batches by expert id -> perm.
__global__ void pre_kernel(const int* __restrict__ pidx, int* __restrict__ perm,
                           float* __restrict__ out, int zero_n, int do_sort)
{
    const int g = blockIdx.x, t = threadIdx.x;
    const int idx = g * 256 + t;
    if (idx < zero_n) out[idx] = 0.f;
    if (do_sort && g == 0) {
        __shared__ int cnt[NE];
        __shared__ int base[NE];
        if (t < NE) cnt[t] = 0;
        __syncthreads();
        const int e = pidx[t];
        const int r = atomicAdd(&cnt[e], 1);
        __syncthreads();
        if (t == 0) {
            int s = 0;
            for (int i = 0; i < NE; ++i) { base[i] = s; s += cnt[i]; }
        }
        __syncthreads();
        perm[base[e] + r] = t;
    }
}

// Z = T2 (128 x 512) x W^T; out[b,l] = sum_i Z[l,i] * t1[b,l,i]
//
// EXACT R5 structure (best: 82 us) with ONE change: the iteration is
// ROTATED so the stage-write of tile kt+1 (the vmcnt consumer of pa/pb)
// sits at the TOP of iter kt, and the reload of pa/pb (tile kt+2)
// immediately follows. Loads therefore fly a FULL iteration (stage(kt)
// -> stage(kt+1)) instead of R5's ~compute-phase, covering the
// 600-900cyc L3/HBM latency of this L2-thrashing working set.
// Legality: buf nxt was last READ in iter kt-1, and the barrier we just
// crossed orders those reads before our writes.
// lb(512,4): acc[2][4]=32 AGPR + ~60 VGPR, no spill (R8 lesson: the
// 64-AGPR acc variant spills at 4 waves/SIMD — stay with acc[2][4]).
template <bool USE_PERM>
__global__ __launch_bounds__(512, 4) void pdot_kernel(
    const float* __restrict__ t1, const float* __restrict__ t2,
    const int* __restrict__ pidx, const float* __restrict__ wgt,
    const int* __restrict__ perm, float* __restrict__ out)
{
    __shared__ unsigned short sm[2][BUFSZ];   // [buf][ sA(128 rows) | sB(128 rows) ]

    const int g  = blockIdx.x;
    const int x  = g & 7;                 // XCD
    const int s  = g >> 3;                // per-XCD sequence 0..127
    const int slot = x * 32 + (s >> 2);   // expert-sorted batch slot
    const int b  = USE_PERM ? perm[slot] : slot;
    const int it = s & 3;
    const int i0 = it * BI;

    const int t  = threadIdx.x;
    const int w  = t >> 6;         // wave 0..7
    const int wv = w & 3;          // l-group: rows wv*32..wv*32+31
    const int ih = w >> 2;         // i-half: cols ih*64..ih*64+63 of the tile
    const int ln = t & 63;
    const int nh = ln & 15;
    const int qd = ln >> 4;

    const int e = pidx[b];
    const float* aPtr = t2  + (size_t)b * (NL * ND2);
    const float* bPtr = wgt + (size_t)e * (ND1 * ND2) + (size_t)i0 * ND2;
    const float* t1p  = t1  + (size_t)b * (NL * ND1) + i0 + ih * 64;

    float4_t acc[2][4];
    #pragma unroll
    for (int i = 0; i < 2; ++i)
        #pragma unroll
        for (int j = 0; j < 4; ++j) {
            float4_t z = {0.f, 0.f, 0.f, 0.f};
            acc[i][j] = z;
        }

    // staging map: A tile 128x64 fp32 = 2048 float4; 512 threads -> 4 each.
    // pass p covers rows p*32..p*32+31; lane (t&15) owns one 16B chunk.
    const int s_row = t >> 4;          // 0..31, +p*32
    const int s_kq  = (t & 15) * 4;
    const size_t sOff = (size_t)s_row * ND2 + s_kq;
    const int wOffA = s_row * LDST + s_kq;
    const int wOffB = (NL + s_row) * LDST + s_kq;

    float4_t pa[4], pb[4];   // in-flight prefetch (32 VGPRs)

    // ---- prologue: load+stage tile 0 into buf0; issue loads of tile 1 ----
    #pragma unroll
    for (int p = 0; p < 4; ++p) {
        pa[p] = *(const float4_t*)(aPtr + sOff + (size_t)p * (32 * ND2));
        pb[p] = *(const float4_t*)(bPtr + sOff + (size_t)p * (32 * ND2));
    }
    #pragma unroll
    for (int p = 0; p < 4; ++p) {
        *(ushort4_t*)(&sm[0][wOffA + p * (32 * LDST)]) = cvt4(pa[p]);
        *(ushort4_t*)(&sm[0][wOffB + p * (32 * LDST)]) = cvt4(pb[p]);
    }
    #pragma unroll
    for (int p = 0; p < 4; ++p) {
        pa[p] = *(const float4_t*)(aPtr + sOff + BK + (size_t)p * (32 * ND2));
        pb[p] = *(const float4_t*)(bPtr + sOff + BK + (size_t)p * (32 * ND2));
    }
    __builtin_amdgcn_sched_barrier(0);
    asm volatile("s_waitcnt lgkmcnt(0)" ::: "memory");
    __builtin_amdgcn_sched_barrier(0);
    __builtin_amdgcn_s_barrier();
    __builtin_amdgcn_sched_barrier(0);

    #pragma unroll
    for (int kt = 0; kt < NKT; ++kt) {
        const int cur = kt & 1;
        const int nxt = cur ^ 1;
        const unsigned short* cA = &sm[cur][0];
        const unsigned short* cB = &sm[cur][NL * LDST];

        // ---- TOP: stage tile kt+1 into buf nxt (pa/pb flew a full iter) ----
        if (kt < NKT - 1) {
            #pragma unroll
            for (int p = 0; p < 4; ++p) {
                *(ushort4_t*)(&sm[nxt][wOffA + p * (32 * LDST)]) = cvt4(pa[p]);
                *(ushort4_t*)(&sm[nxt][wOffB + p * (32 * LDST)]) = cvt4(pb[p]);
            }
            // ---- immediately reload pa/pb with tile kt+2 (full-iter flight) ----
            if (kt < NKT - 2) {
                const size_t k0 = (size_t)(kt + 2) * BK;
                #pragma unroll
                for (int p = 0; p < 4; ++p) {
                    pa[p] = *(const float4_t*)(aPtr + sOff + k0 + (size_t)p * (32 * ND2));
                    pb[p] = *(const float4_t*)(bPtr + sOff + k0 + (size_t)p * (32 * ND2));
                }
                __builtin_amdgcn_sched_barrier(0);
            }
        }

        // ---- compute tile kt from buf cur (published by previous barrier) ----
        #pragma unroll
        for (int ks = 0; ks < 2; ++ks) {
            const int kf = ks * 32 + qd * 8;
            const int ra = wv * 32 + nh;
            bf16x8_t af0 = __builtin_bit_cast(bf16x8_t, *(const ushort8_t*)(&cA[(ra     ) * LDST + kf]));
            bf16x8_t af1 = __builtin_bit_cast(bf16x8_t, *(const ushort8_t*)(&cA[(ra + 16) * LDST + kf]));
            bf16x8_t bv[4];
            #pragma unroll
            for (int ns = 0; ns < 4; ++ns)
                bv[ns] = __builtin_bit_cast(bf16x8_t, *(const ushort8_t*)(&cB[(ih * 64 + ns * 16 + nh) * LDST + kf]));
            __builtin_amdgcn_s_setprio(1);
            #pragma unroll
            for (int ns = 0; ns < 4; ++ns) {
                acc[0][ns] = __builtin_amdgcn_mfma_f32_16x16x32_bf16(af0, bv[ns], acc[0][ns], 0, 0, 0);
                acc[1][ns] = __builtin_amdgcn_mfma_f32_16x16x32_bf16(af1, bv[ns], acc[1][ns], 0, 0, 0);
            }
            __builtin_amdgcn_s_setprio(0);
        }

        // ---- single lgkm+barrier per iteration ----
        if (kt < NKT - 1) {
            asm volatile("s_waitcnt lgkmcnt(0)" ::: "memory");  // my stage-writes + frag-reads retired
            __builtin_amdgcn_sched_barrier(0);
            __builtin_amdgcn_s_barrier();
            __builtin_amdgcn_sched_barrier(0);
        }
    }

    // epilogue: out[b,l] += sum over this wave's i-columns of Z[l,i]*t1[l,i]
    // C/D: col(n=i) = ih*64 + ns*16 + nh, row(m=l) = wv*32 + ms*16 + qd*4 + r
    #pragma unroll
    for (int ms = 0; ms < 2; ++ms) {
        #pragma unroll
        for (int r = 0; r < 4; ++r) {
            const int row = wv * 32 + ms * 16 + qd * 4 + r;
            float ps = 0.f;
            #pragma unroll
            for (int ns = 0; ns < 4; ++ns) {
                const float tv = t1p[(size_t)row * ND1 + ns * 16 + nh];
                ps += acc[ms][ns][r] * tv;
            }
            ps += __shfl_xor(ps, 1);
            ps += __shfl_xor(ps, 2);
            ps += __shfl_xor(ps, 4);
            ps += __shfl_xor(ps, 8);
            if (nh == 0) atomicAdd(&out[b * NL + row], ps);
        }
    }
}

extern "C" void kernel_launch(void* const* d_in, const int* in_sizes, int n_in,
                              void* d_out, int out_size, void* d_ws, size_t ws_size,
                              hipStream_t stream)
{
    const float* t1  = (const float*)d_in[0];
    const float* t2  = (const float*)d_in[1];
    const int* pidx  = (const int*)d_in[2];
    const float* wgt = (const float*)d_in[3];
    float* out = (float*)d_out;

    const int zero_blocks = (out_size + 255) / 256;
    const bool have_ws = ws_size >= NB * sizeof(int);
    int* perm = have_ws ? (int*)d_ws : nullptr;

    pre_kernel<<<dim3(zero_blocks), dim3(256), 0, stream>>>(pidx, perm, out, out_size, have_ws ? 1 : 0);

    if (have_ws)
        pdot_kernel<true><<<dim3(NB * (ND1 / BI)), dim3(512), 0, stream>>>(t1, t2, pidx, wgt, perm, out);
    else
        pdot_kernel<false><<<dim3(NB * (ND1 / BI)), dim3(512), 0, stream>>>(t1, t2, pidx, wgt, nullptr, out);
}